// Round 1
// baseline (704.547 us; speedup 1.0000x reference)
//
#include <hip/hip_runtime.h>
#include <hip/hip_bf16.h>

#define BB 8
#define SS 4096
#define HH 32
#define DD 128
#define HID 4096
#define TOK 16   // tokens per block in kernel 1

// ---------------------------------------------------------------------------
// Kernel 1: per-head scores + global argmax via packed-u64 atomicMax.
// Packing: high 32 = order-preserving uint of score, low 32 = 0xFFFFFFFF - s
// so equal scores prefer the SMALLER s (jnp.argmax first-occurrence).
// bs bias omitted: constant per head -> argmax-invariant.
// ---------------------------------------------------------------------------
__global__ __launch_bounds__(256) void score_argmax_kernel(
    const float* __restrict__ x, const int* __restrict__ mask,
    const float* __restrict__ Ws, unsigned long long* __restrict__ best) {
  const int t = threadIdx.x;
  const int blk = blockIdx.x;
  const int b = blk / (SS / TOK);
  const int s0 = (blk % (SS / TOK)) * TOK;

  const int hsub = t >> 5;            // 0..7: head sub-index within a pass
  const int lane_d = (t & 31) * 4;    // d-offset within the head

  // Preload this thread's Ws fragment: pass p covers head h = p*8 + hsub.
  float4 w[4];
#pragma unroll
  for (int p = 0; p < 4; ++p) {
    w[p] = *(const float4*)(Ws + (p * 8 + hsub) * DD + lane_d);
  }

  float bestv[4];
  int bests[4];
#pragma unroll
  for (int p = 0; p < 4; ++p) { bestv[p] = -3.0e38f; bests[p] = 0; }

  for (int i = 0; i < TOK; ++i) {
    const int s = s0 + i;
    const float* row = x + ((size_t)b * SS + s) * HID;
    const bool valid = (mask[b * SS + s] != 0);
#pragma unroll
    for (int p = 0; p < 4; ++p) {
      float4 v = *(const float4*)(row + p * 1024 + t * 4);
      float sc = v.x * w[p].x + v.y * w[p].y + v.z * w[p].z + v.w * w[p].w;
      // butterfly sum over the 32-lane group (stays within a 64-lane wave)
      sc += __shfl_xor(sc, 1);
      sc += __shfl_xor(sc, 2);
      sc += __shfl_xor(sc, 4);
      sc += __shfl_xor(sc, 8);
      sc += __shfl_xor(sc, 16);
      if (!valid) sc = -1e9f;
      if (sc > bestv[p]) { bestv[p] = sc; bests[p] = s; }  // strict > keeps first s
    }
  }

  if ((t & 31) == 0) {
#pragma unroll
    for (int p = 0; p < 4; ++p) {
      const int h = p * 8 + hsub;
      unsigned int ub = __float_as_uint(bestv[p]);
      ub = (ub & 0x80000000u) ? ~ub : (ub | 0x80000000u);  // order-preserving map
      unsigned long long pk =
          ((unsigned long long)ub << 32) | (unsigned long long)(0xFFFFFFFFu - (unsigned)bests[p]);
      atomicMax(&best[b * HH + h], pk);
    }
  }
}

// ---------------------------------------------------------------------------
// Kernel 2: gather winning token per (b,h), dot with Wc, reduce, + bc.
// ---------------------------------------------------------------------------
__global__ __launch_bounds__(256) void gather_dot_kernel(
    const float* __restrict__ x, const float* __restrict__ Wc,
    const float* __restrict__ bc, const unsigned long long* __restrict__ best,
    float* __restrict__ out) {
  const int b = blockIdx.x;
  const int t = threadIdx.x;
  const int d = t & 127;
  const int h0 = t >> 7;  // 0 or 1

  float acc = 0.f;
  for (int h = h0; h < HH; h += 2) {
    unsigned long long pk = best[b * HH + h];
    const int s = (int)(0xFFFFFFFFu - (unsigned)(pk & 0xFFFFFFFFull));
    acc += x[((size_t)b * SS + s) * HID + h * DD + d] * Wc[h * DD + d];
  }

  __shared__ float red[256];
  red[t] = acc;
  __syncthreads();
  for (int off = 128; off > 0; off >>= 1) {
    if (t < off) red[t] += red[t + off];
    __syncthreads();
  }
  if (t == 0) out[b] = red[0] + bc[0];
}

extern "C" void kernel_launch(void* const* d_in, const int* in_sizes, int n_in,
                              void* d_out, int out_size, void* d_ws, size_t ws_size,
                              hipStream_t stream) {
  const float* x   = (const float*)d_in[0];
  const int* mask  = (const int*)d_in[1];
  const float* Ws  = (const float*)d_in[2];
  // d_in[3] = bs (unused: argmax-invariant per-head constant)
  const float* Wc  = (const float*)d_in[4];
  const float* bc  = (const float*)d_in[5];
  float* out = (float*)d_out;

  unsigned long long* best = (unsigned long long*)d_ws;

  hipMemsetAsync(d_ws, 0, BB * HH * sizeof(unsigned long long), stream);
  score_argmax_kernel<<<BB * (SS / TOK), 256, 0, stream>>>(x, mask, Ws, best);
  gather_dot_kernel<<<BB, 256, 0, stream>>>(x, Wc, bc, best, out);
}

// Round 3
// 691.586 us; speedup vs baseline: 1.0187x; 1.0187x over previous
//
#include <hip/hip_runtime.h>
#include <hip/hip_bf16.h>

#define BB 8
#define SS 4096
#define HH 32
#define DD 128
#define HID 4096
#define TOK 8   // tokens per block in kernel 1

// xor-swizzle add within 8-lane groups (BitMode: offset=(xor<<10)|(or<<5)|and)
// Pattern must be a compile-time constant -> template parameter.
template <int PAT>
__device__ __forceinline__ float swz(float v) {
  return __int_as_float(__builtin_amdgcn_ds_swizzle(__float_as_int(v), PAT));
}

// ---------------------------------------------------------------------------
// Kernel 1: per-head scores + global argmax via packed-u64 atomicMax.
// Layout: head h = t>>3 (all 32 heads in one pass), lane-in-head l = t&7.
// Load k (k=0..3): float4 at h*128 + k*32 + l*4 -> each 8-lane group reads one
// contiguous 128 B line per instruction (perfect per-line coalescing).
// Reduce over the 8 lanes with a 3-level ds_swizzle butterfly.
// Packing: high 32 = order-preserving uint of score, low 32 = 0xFFFFFFFF - s
// so equal scores prefer the SMALLER s (jnp.argmax first-occurrence).
// bs bias omitted: constant per head -> argmax-invariant.
// ---------------------------------------------------------------------------
__global__ __launch_bounds__(256) void score_argmax_kernel(
    const float* __restrict__ x, const int* __restrict__ mask,
    const float* __restrict__ Ws, unsigned long long* __restrict__ best) {
  const int t = threadIdx.x;
  const int blk = blockIdx.x;
  const int b = blk / (SS / TOK);
  const int s0 = (blk % (SS / TOK)) * TOK;

  const int h = t >> 3;   // head 0..31
  const int l = t & 7;    // lane within head

  // Preload this thread's Ws fragment (matches the x load layout).
  float4 w[4];
#pragma unroll
  for (int k = 0; k < 4; ++k) {
    w[k] = *(const float4*)(Ws + h * DD + k * 32 + l * 4);
  }

  float bestv = -3.0e38f;
  int bests = 0;

  const float* base = x + ((size_t)b * SS + s0) * HID + h * DD + l * 4;

  for (int i = 0; i < TOK; ++i) {
    const int s = s0 + i;
    const float* row = base + (size_t)i * HID;
    const bool valid = (mask[b * SS + s] != 0);

    float4 v0 = *(const float4*)(row);
    float4 v1 = *(const float4*)(row + 32);
    float4 v2 = *(const float4*)(row + 64);
    float4 v3 = *(const float4*)(row + 96);

    float sc = v0.x * w[0].x + v0.y * w[0].y + v0.z * w[0].z + v0.w * w[0].w;
    sc += v1.x * w[1].x + v1.y * w[1].y + v1.z * w[1].z + v1.w * w[1].w;
    sc += v2.x * w[2].x + v2.y * w[2].y + v2.z * w[2].z + v2.w * w[2].w;
    sc += v3.x * w[3].x + v3.y * w[3].y + v3.z * w[3].z + v3.w * w[3].w;

    // 3-level xor butterfly over the 8-lane group
    sc += swz<0x041F>(sc);  // xor 1
    sc += swz<0x081F>(sc);  // xor 2
    sc += swz<0x101F>(sc);  // xor 4

    if (!valid) sc = -1e9f;
    if (sc > bestv) { bestv = sc; bests = s; }  // strict > keeps first s
  }

  if (l == 0) {
    unsigned int ub = __float_as_uint(bestv);
    ub = (ub & 0x80000000u) ? ~ub : (ub | 0x80000000u);  // order-preserving map
    unsigned long long pk =
        ((unsigned long long)ub << 32) | (unsigned long long)(0xFFFFFFFFu - (unsigned)bests);
    atomicMax(&best[b * HH + h], pk);
  }
}

// ---------------------------------------------------------------------------
// Kernel 2: gather winning token per (b,h), dot with Wc, reduce, + bc.
// ---------------------------------------------------------------------------
__global__ __launch_bounds__(256) void gather_dot_kernel(
    const float* __restrict__ x, const float* __restrict__ Wc,
    const float* __restrict__ bc, const unsigned long long* __restrict__ best,
    float* __restrict__ out) {
  const int b = blockIdx.x;
  const int t = threadIdx.x;
  const int d = t & 127;
  const int h0 = t >> 7;  // 0 or 1

  float acc = 0.f;
  for (int h = h0; h < HH; h += 2) {
    unsigned long long pk = best[b * HH + h];
    const int s = (int)(0xFFFFFFFFu - (unsigned)(pk & 0xFFFFFFFFull));
    acc += x[((size_t)b * SS + s) * HID + h * DD + d] * Wc[h * DD + d];
  }

  __shared__ float red[256];
  red[t] = acc;
  __syncthreads();
  for (int off = 128; off > 0; off >>= 1) {
    if (t < off) red[t] += red[t + off];
    __syncthreads();
  }
  if (t == 0) out[b] = red[0] + bc[0];
}

extern "C" void kernel_launch(void* const* d_in, const int* in_sizes, int n_in,
                              void* d_out, int out_size, void* d_ws, size_t ws_size,
                              hipStream_t stream) {
  const float* x   = (const float*)d_in[0];
  const int* mask  = (const int*)d_in[1];
  const float* Ws  = (const float*)d_in[2];
  // d_in[3] = bs (unused: argmax-invariant per-head constant)
  const float* Wc  = (const float*)d_in[4];
  const float* bc  = (const float*)d_in[5];
  float* out = (float*)d_out;

  unsigned long long* best = (unsigned long long*)d_ws;

  (void)hipMemsetAsync(d_ws, 0, BB * HH * sizeof(unsigned long long), stream);
  score_argmax_kernel<<<BB * (SS / TOK), 256, 0, stream>>>(x, mask, Ws, best);
  gather_dot_kernel<<<BB, 256, 0, stream>>>(x, Wc, bc, best, out);
}